// Round 6
// baseline (49050.198 us; speedup 1.0000x reference)
//
#include <hip/hip_runtime.h>
#include <stdint.h>

typedef __fp16 f16x2 __attribute__((ext_vector_type(2)));
typedef __fp16 f16x8 __attribute__((ext_vector_type(8)));
typedef uint32_t u32x4 __attribute__((ext_vector_type(4)));
typedef unsigned long long ull;

#define SEQ  8192
#define HDIM 2048
#define DIN  256
#define DOUT 64

__device__ __forceinline__ f16x2 pk(float lo, float hi) {
    return __builtin_amdgcn_cvt_pkrtz(lo, hi);   // fp32 pair -> packed f16
}
__device__ __forceinline__ f16x2 pk2(float2 v) { return pk(v.x, v.y); }
__device__ __forceinline__ uint32_t h2u(f16x2 h) { return __builtin_bit_cast(uint32_t, h); }
__device__ __forceinline__ float sigf(float x) { return 1.0f / (1.0f + __expf(-x)); }
__device__ __forceinline__ float tanh_fast(float x) { return 2.0f * sigf(2.0f * x) - 1.0f; }

// LDS skews: chunk c's words land contiguously; chunks hit disjoint bank groups.
__device__ __forceinline__ int skH(int j) { return j + 4 * (j >> 7); }  // max 1051
__device__ __forceinline__ int skX(int j) { return j + 4 * (j >> 4); }  // max 155

// 32B load, MALL-coherent (sc1), single RTT; early-clobber so dest never aliases addr.
__device__ __forceinline__ void ld32_sc1(const ull* p, u32x4& a, u32x4& b) {
    asm volatile("global_load_dwordx4 %0, %2, off sc1\n\t"
                 "global_load_dwordx4 %1, %2, off offset:16 sc1\n\t"
                 "s_waitcnt vmcnt(0)"
                 : "=&v"(a), "=&v"(b) : "v"(p) : "memory");
}
// 16B counter-sector load, MALL-coherent (4 packed sub-counters in one line)
__device__ __forceinline__ u32x4 ld_ctr4(const uint32_t* p) {
    u32x4 v;
    asm volatile("global_load_dwordx4 %0, %1, off sc1\n\t"
                 "s_waitcnt vmcnt(0)"
                 : "=&v"(v) : "v"(p) : "memory");
    return v;
}

__global__ void __launch_bounds__(320, 1)
lstm_persist(const float2* __restrict__ x2,       // [8192*128] fp32 pairs
             const float2* __restrict__ hprev2,   // [1024]
             const float*  __restrict__ cprev,    // [2048]
             const float*  __restrict__ wih,      // [8192*256]
             const float*  __restrict__ whh,      // [8192*2048]
             const float*  __restrict__ bih,      // [8192]
             const float*  __restrict__ bhh,      // [8192]
             const float2* __restrict__ wfc2,     // [64*1024]
             const float*  __restrict__ bfc,      // [64]
             float* __restrict__ out,             // 528384 fp32
             uint32_t* __restrict__ hs_w,         // [256 blocks][32 rows][1024 words] PRIVATE
             ull* __restrict__ htag,              // [2][1024] tagged-word mailbox
             uint32_t* __restrict__ ctr)          // [2 parity][8 lines x 4 subctrs], 512B stride, zeroed
{
    const int tid = threadIdx.x;
    const bool worker = (tid < 256);   // waves 0..3 compute; wave 4 = gate poller
    const int b   = blockIdx.x;
    const int wv  = tid >> 6;        // worker wave id 0..3 -> units 2wv, 2wv+1
    const int l   = tid & 63;        // lane
    const int g   = l >> 4;          // gate 0..3 (i,f,g,o)
    const int p   = (l >> 3) & 1;    // unit parity
    const int c   = l & 7;           // k-chunk 0..7

    __shared__ __align__(16) uint32_t smem[12672];
    uint32_t* ldsH0 = smem;            // 1056 words
    uint32_t* ldsH1 = smem + 1056;     // 1056
    uint32_t* ldsX0 = smem + 2112;     // 160 (x row t,   t even)
    uint32_t* ldsX1 = smem + 2272;     // 160 (x row t,   t odd)
    uint32_t* ldsFlag = smem + 2432;   // poller -> workers: highest gate-passed tag
    // FC-phase reuse:
    uint32_t* hsl = smem;              // 32*132
    uint32_t* wfl = smem + 4224;       // 64*132

    uint32_t* hs_priv = hs_w + (size_t)b * 32 * 1024;   // this block's FC rows

    if (tid == 0) *ldsFlag = 0;

    // ---------------- prologue: weights -> registers (fp32 -> f16), workers only ----------------
    const int unit = 8 * b + 2 * wv + p;          // this lane's hidden unit (workers)
    const int r    = g * 2048 + unit;             // this lane's gate-row
    f16x2 wh[128];                                // W_hh[r, 256c .. 256c+256)
    f16x2 wx[16];                                 // W_ih[r, 32c .. 32c+32)
    float cloc = 0.f, bsum = 0.f;
    if (worker) {
        const float4* ptr = (const float4*)(whh + (size_t)r * 2048 + 256 * c);
#pragma unroll
        for (int q = 0; q < 64; ++q) {
            float4 v = ptr[q];
            wh[2*q+0] = pk(v.x, v.y);
            wh[2*q+1] = pk(v.z, v.w);
        }
        const float4* ptr2 = (const float4*)(wih + (size_t)r * 256 + 32 * c);
#pragma unroll
        for (int q = 0; q < 8; ++q) {
            float4 v = ptr2[q];
            wx[2*q+0] = pk(v.x, v.y);
            wx[2*q+1] = pk(v.z, v.w);
        }
        // h version 0 (hprev) -> slot 0
#pragma unroll
        for (int k = 0; k < 4; ++k) {
            int j = tid + 256 * k;
            ldsH0[skH(j)] = h2u(pk2(hprev2[j]));
        }
        cloc = cprev[unit];
        bsum = bih[r] + bhh[r];
    }
    if (tid < 128) ldsX0[skX(tid)] = h2u(pk2(x2[tid]));
    float2 xw = {0.f, 0.f};                       // x pipeline depth-2: row t+1 at top of iter t
    if (tid < 128) xw = x2[128 + tid];

    float hloc = 0.f;
    u32x4 prev_pays = {0, 0, 0, 0};               // deferred hs row (swept last iter)
    int  prev_row = 0;
    bool prev_own = false;
    const ull deadline = __builtin_amdgcn_s_memrealtime() + 60000000ull; // watchdog: bail, no hang
    __syncthreads();

    if (!worker) {
        // ================= poller wave: runs the counter gate continuously =================
        // Barrier alignment: one extra barrier here (epoch 0), then one per step.
        bool bail = false;
        __syncthreads();
        for (int t = 1; t < SEQ; ++t) {
            if (!bail) {
                const int par = t & 1;
                const uint32_t target = (uint32_t)((t + (t & 1)) >> 1) * 8u;
                const uint32_t* cbase = ctr + (size_t)par * 8 * 128;
                int spins = 0;
                for (;;) {
                    bool ok = true;
                    if (l < 8) {
                        u32x4 v = ld_ctr4(cbase + (size_t)l * 128);
                        ok = (v[0] >= target) && (v[1] >= target) &&
                             (v[2] >= target) && (v[3] >= target);
                    }
                    if (__all(ok)) break;
                    if (spins++ > 0) {
                        if (__builtin_amdgcn_s_memrealtime() > deadline) { bail = true; break; }
                        __builtin_amdgcn_s_sleep(1);
                    }
                }
            }
            if (l == 0)
                __hip_atomic_store(ldsFlag, bail ? 0xFFFFFFFFu : (uint32_t)t,
                                   __ATOMIC_RELAXED, __HIP_MEMORY_SCOPE_WORKGROUP);
            __syncthreads();
        }
    } else {
        // ================= worker waves: sequential scan, ONE barrier per step =================
        for (int t = 0; t < SEQ; ++t) {
            uint32_t* ldsH  = (t & 1) ? ldsH1 : ldsH0;
            uint32_t* ldsXc = (t & 1) ? ldsX1 : ldsX0;   // row t (consumed now)
            uint32_t* ldsXn = (t & 1) ? ldsX0 : ldsX1;   // row t+1 (staged from regs)

            // x-projection (off critical path), 8-way ILP accumulators
            float accs[8];
#pragma unroll
            for (int q = 0; q < 8; ++q) accs[q] = 0.f;
            {
                const f16x8* xp = (const f16x8*)(ldsXc + 20 * c);
#pragma unroll
                for (int q = 0; q < 4; ++q) {
                    f16x8 xv = xp[q];
#pragma unroll
                    for (int d = 0; d < 4; ++d) {
                        f16x2 hv = {xv[2*d], xv[2*d+1]};
                        int idx = 4 * q + d;
                        accs[idx & 7] = __builtin_amdgcn_fdot2(wx[idx], hv, accs[idx & 7], false);
                    }
                }
            }
            // stage row t+1 into the other ldsX buffer from REGISTERS
            if (tid < 128 && t + 1 < SEQ) ldsXn[skX(tid)] = h2u(pk2(xw));

            // ---- exchange ----
            if (t > 0) {
                const int par = t & 1;
                // 1) readiness: spin on the LDS flag the poller wave maintains.
                //    Zero fabric traffic; observation lag ~LDS latency after the
                //    poller sees the gate pass (poll RTT fully overlapped with
                //    the staging above and last step's matvec).
                {
                    int spins = 0;
                    for (;;) {
                        uint32_t fv = __hip_atomic_load(ldsFlag, __ATOMIC_RELAXED,
                                                        __HIP_MEMORY_SCOPE_WORKGROUP);
                        if (fv >= (uint32_t)t) break;
                        if (++spins > 64) {
                            spins = 0;
                            if (__builtin_amdgcn_s_memrealtime() > deadline) break;
                            __builtin_amdgcn_s_sleep(1);
                        }
                    }
                }
                // 2) one-shot data read (32B quad = producer block tid's 4 words), tag-validated
                const ull* mb = htag + (size_t)par * 1024 + 4 * tid;
                u32x4 qa, qb;
                for (;;) {
                    ld32_sc1(mb, qa, qb);
                    if (qa[1] == (uint32_t)t && qa[3] == (uint32_t)t &&
                        qb[1] == (uint32_t)t && qb[3] == (uint32_t)t) break;
                    if (__builtin_amdgcn_s_memrealtime() > deadline) break;
                    __builtin_amdgcn_s_sleep(1);
                }
                u32x4 pays = {qa[0], qa[2], qb[0], qb[2]};
                *(u32x4*)(ldsH + skH(4 * tid)) = pays;          // contiguous quad -> ds_write_b128
                // DEFERRED hs store: last iteration's swept row; ack drains under compute
                if (prev_own)
                    *(u32x4*)(hs_priv + (size_t)(prev_row & 31) * 1024 + 4 * tid) = prev_pays;
                prev_pays = pays;
                prev_row  = t - 1;
                prev_own  = ((t - 1) >> 5) == b;
            }
            // prefetch x row t+2 into regs (never outstanding at a blocking wait)
            if (tid < 128 && t + 2 < SEQ) xw = x2[(size_t)(t + 2) * 128 + tid];

            __syncthreads();

            // recurrent matvec from register weights, h via LDS broadcast (8-way ILP)
            {
                const f16x8* hp = (const f16x8*)(ldsH + 132 * c);
#pragma unroll
                for (int q = 0; q < 32; ++q) {
                    f16x8 hv8 = hp[q];
#pragma unroll
                    for (int d = 0; d < 4; ++d) {
                        f16x2 hh = {hv8[2*d], hv8[2*d+1]};
                        int idx = 4 * q + d;
                        accs[idx & 7] = __builtin_amdgcn_fdot2(wh[idx], hh, accs[idx & 7], false);
                    }
                }
            }
            float acc = ((accs[0] + accs[1]) + (accs[2] + accs[3]))
                      + ((accs[4] + accs[5]) + (accs[6] + accs[7]));
            // reduce over the 8 k-chunk lanes (c = bits 0..2 of lane)
            acc += __shfl_xor(acc, 1);
            acc += __shfl_xor(acc, 2);
            acc += __shfl_xor(acc, 4);

            // one v_exp for all four gates (lane-specialized), then intra-wave gather
            float z = acc + bsum;
            const bool isg = (g == 2);
            float s  = sigf(isg ? 2.0f * z : z);
            float val = isg ? (2.0f * s - 1.0f) : s;
            const int p8 = l & 8;
            float iv = __shfl(val, p8 + 0);
            float fv = __shfl(val, p8 + 16);
            float gv = __shfl(val, p8 + 32);
            float ov = __shfl(val, p8 + 48);
            cloc = fv * cloc + iv * gv;
            hloc = ov * tanh_fast(cloc);

            // publish: tagged word per wave, then one sub-counter bump per block
            float h0 = __shfl(hloc, 0);
            float h1 = __shfl(hloc, 8);
            uint32_t pay = h2u(pk(h0, h1));
            if (l == 0) {
                ull tv = ((ull)(uint32_t)(t + 1) << 32) | (ull)pay;
                __hip_atomic_store(htag + (size_t)((t + 1) & 1) * 1024 + 4 * b + wv,
                                   tv, __ATOMIC_RELAXED, __HIP_MEMORY_SCOPE_AGENT);
                if (wv == 0)
                    atomicAdd(ctr + ((size_t)((t + 1) & 1) * 8 + (b & 7)) * 128 + ((b >> 3) & 3), 1u);
            }
        }
    }

    // epilogue: flush the final deferred row (t=8191 sweep -> row 8190, block 255)
    if (prev_own)
        *(u32x4*)(hs_priv + (size_t)(prev_row & 31) * 1024 + 4 * tid) = prev_pays;

    // hT / cT outputs (fp32): lanes 0 (p=0) and 8 (p=1) of each worker wave hold their unit
    if (worker && (l == 0 || l == 8)) {
        out[(size_t)SEQ * DOUT + unit]        = hloc;
        out[(size_t)SEQ * DOUT + HDIM + unit] = cloc;
    }

    // only block 255 needs h(8191) (= hs row 8191) -> poll tag 8192 (slot 0) on the mailbox
    if (b == 255 && worker) {
        uint32_t pay[4] = {0, 0, 0, 0};
        unsigned got = 0;
        while (got != 0xFu) {
#pragma unroll
            for (int k = 0; k < 4; ++k) {
                if (!(got & (1u << k))) {
                    ull v = __hip_atomic_load(htag + (tid + 256 * k),
                                              __ATOMIC_RELAXED, __HIP_MEMORY_SCOPE_AGENT);
                    if ((uint32_t)(v >> 32) == 8192u) {
                        pay[k] = (uint32_t)v;
                        got |= (1u << k);
                    }
                }
            }
            if (got != 0xFu) {
                if (__builtin_amdgcn_s_memrealtime() > deadline) got = 0xFu;
                __builtin_amdgcn_s_sleep(1);
            }
        }
#pragma unroll
        for (int k = 0; k < 4; ++k)
            hs_priv[(size_t)31 * 1024 + tid + 256 * k] = pay[k];
    }
    __syncthreads();

    // ---------------- output FC: rows [32b, 32b+32), 64 cols, from PRIVATE hs ----------------
    const int cc = tid & 63;
    const int rg = tid >> 6;
    const float bo = bfc[cc];
    float fca[8];
#pragma unroll
    for (int q = 0; q < 8; ++q) fca[q] = 0.f;

    for (int ch = 0; ch < 8; ++ch) {   // 8 chunks of 256 k (128 pair-words)
        if (worker) {
#pragma unroll
            for (int i = 0; i < 16; ++i) { // hs tile: [32 rows][128 words]
                int idx = tid + 256 * i;
                int rr = idx >> 7, kp = idx & 127;
                hsl[rr * 132 + kp] = hs_priv[(size_t)rr * 1024 + ch * 128 + kp]; // own writes
            }
#pragma unroll
            for (int i = 0; i < 32; ++i) { // W_fc tile: [64 cols][128 pair-words]
                int idx = tid + 256 * i;
                int c2 = idx >> 7, kp = idx & 127;
                wfl[c2 * 132 + kp] = h2u(pk2(wfc2[(size_t)c2 * 1024 + ch * 128 + kp]));
            }
        }
        __syncthreads();
        if (worker) {
#pragma unroll 4
            for (int k4 = 0; k4 < 32; ++k4) {
                f16x8 wvv = *(const f16x8*)(wfl + cc * 132 + 4 * k4);
#pragma unroll
                for (int q = 0; q < 8; ++q) {
                    f16x8 hv = *(const f16x8*)(hsl + (rg * 8 + q) * 132 + 4 * k4);
#pragma unroll
                    for (int d = 0; d < 4; ++d) {
                        f16x2 a  = {hv[2*d], hv[2*d+1]};
                        f16x2 bb = {wvv[2*d], wvv[2*d+1]};
                        fca[q] = __builtin_amdgcn_fdot2(a, bb, fca[q], false);
                    }
                }
            }
        }
        __syncthreads();
    }
    if (worker) {
#pragma unroll
        for (int q = 0; q < 8; ++q) {
            size_t row = (size_t)32 * b + rg * 8 + q;
            out[row * DOUT + cc] = sigf(fca[q] + bo);
        }
    }
}

extern "C" void kernel_launch(void* const* d_in, const int* in_sizes, int n_in,
                              void* d_out, int out_size, void* d_ws, size_t ws_size,
                              hipStream_t stream) {
    const float2* x2     = (const float2*)d_in[0];
    const float2* hprev2 = (const float2*)d_in[1];
    const float*  cprev  = (const float*)d_in[2];
    const float*  wih    = (const float*)d_in[3];
    const float*  whh    = (const float*)d_in[4];
    const float*  bih    = (const float*)d_in[5];
    const float*  bhh    = (const float*)d_in[6];
    const float2* wfc2   = (const float2*)d_in[7];
    const float*  bfc    = (const float*)d_in[8];
    float*        out    = (float*)d_out;

    char* ws = (char*)d_ws;
    uint32_t* hs_w = (uint32_t*)ws;                      // 33,554,432 B private hs slices
    ull*      htag = (ull*)(ws + 33554432);              // 16 KB (0xAA != any tag)
    uint32_t* ctr  = (uint32_t*)(ws + 33554432 + 16384); // 16 lines x 512B = 8 KB, zeroed

    hipMemsetAsync(ctr, 0, 8192, stream);   // graph-capturable
    lstm_persist<<<dim3(256), dim3(320), 0, stream>>>(
        x2, hprev2, cprev, wih, whh, bih, bhh, wfc2, bfc,
        out, hs_w, htag, ctr);
}

// Round 7
// 35457.254 us; speedup vs baseline: 1.3834x; 1.3834x over previous
//
#include <hip/hip_runtime.h>
#include <stdint.h>

typedef __fp16 f16x2 __attribute__((ext_vector_type(2)));
typedef __fp16 f16x8 __attribute__((ext_vector_type(8)));
typedef uint32_t u32x4 __attribute__((ext_vector_type(4)));
typedef unsigned long long ull;

#define SEQ  8192
#define HDIM 2048
#define DIN  256
#define DOUT 64

__device__ __forceinline__ f16x2 pk(float lo, float hi) {
    return __builtin_amdgcn_cvt_pkrtz(lo, hi);   // fp32 pair -> packed f16
}
__device__ __forceinline__ f16x2 pk2(float2 v) { return pk(v.x, v.y); }
__device__ __forceinline__ uint32_t h2u(f16x2 h) { return __builtin_bit_cast(uint32_t, h); }
__device__ __forceinline__ float sigf(float x) { return 1.0f / (1.0f + __expf(-x)); }
__device__ __forceinline__ float tanh_fast(float x) { return 2.0f * sigf(2.0f * x) - 1.0f; }

// LDS skews: chunk c's words land contiguously; chunks hit disjoint bank groups.
__device__ __forceinline__ int skH(int j) { return j + 4 * (j >> 7); }  // max 1051
__device__ __forceinline__ int skX(int j) { return j + 4 * (j >> 4); }  // max 155

// 32B load, MALL-coherent (sc1), single RTT; early-clobber so dest never aliases addr.
__device__ __forceinline__ void ld32_sc1(const ull* p, u32x4& a, u32x4& b) {
    asm volatile("global_load_dwordx4 %0, %2, off sc1\n\t"
                 "global_load_dwordx4 %1, %2, off offset:16 sc1\n\t"
                 "s_waitcnt vmcnt(0)"
                 : "=&v"(a), "=&v"(b) : "v"(p) : "memory");
}
// 16B counter-sector load, MALL-coherent (4 packed sub-counters in one line)
__device__ __forceinline__ u32x4 ld_ctr4(const uint32_t* p) {
    u32x4 v;
    asm volatile("global_load_dwordx4 %0, %1, off sc1\n\t"
                 "s_waitcnt vmcnt(0)"
                 : "=&v"(v) : "v"(p) : "memory");
    return v;
}
// FUSED probe: counter line + 32B data quad in ONE round trip (single vmcnt wait).
__device__ __forceinline__ void probe_sc1(const uint32_t* cp, const ull* mb,
                                          u32x4& cv, u32x4& a, u32x4& b) {
    asm volatile("global_load_dwordx4 %0, %3, off sc1\n\t"
                 "global_load_dwordx4 %1, %4, off sc1\n\t"
                 "global_load_dwordx4 %2, %4, off offset:16 sc1\n\t"
                 "s_waitcnt vmcnt(0)"
                 : "=&v"(cv), "=&v"(a), "=&v"(b)
                 : "v"(cp), "v"(mb) : "memory");
}

__global__ void __launch_bounds__(256, 1)
lstm_persist(const float2* __restrict__ x2,       // [8192*128] fp32 pairs
             const float2* __restrict__ hprev2,   // [1024]
             const float*  __restrict__ cprev,    // [2048]
             const float*  __restrict__ wih,      // [8192*256]
             const float*  __restrict__ whh,      // [8192*2048]
             const float*  __restrict__ bih,      // [8192]
             const float*  __restrict__ bhh,      // [8192]
             const float2* __restrict__ wfc2,     // [64*1024]
             const float*  __restrict__ bfc,      // [64]
             float* __restrict__ out,             // 528384 fp32
             uint32_t* __restrict__ hs_w,         // [256 blocks][32 rows][1024 words] PRIVATE
             ull* __restrict__ htag,              // [2][1024] tagged-word mailbox
             uint32_t* __restrict__ ctr)          // [2 parity][8 lines x 4 subctrs], 512B stride, zeroed
{
    const int tid = threadIdx.x;
    const int b   = blockIdx.x;
    const int wv  = tid >> 6;        // wave id 0..3 -> units 2wv, 2wv+1
    const int l   = tid & 63;        // lane
    const int g   = l >> 4;          // gate 0..3 (i,f,g,o)
    const int p   = (l >> 3) & 1;    // unit parity
    const int c   = l & 7;           // k-chunk 0..7

    __shared__ __align__(16) uint32_t smem[12672];
    uint32_t* ldsH0 = smem;            // 1056 words
    uint32_t* ldsH1 = smem + 1056;     // 1056
    uint32_t* ldsX0 = smem + 2112;     // 160 (x row t,   t even)
    uint32_t* ldsX1 = smem + 2272;     // 160 (x row t,   t odd)
    // FC-phase reuse:
    uint32_t* hsl = smem;              // 32*132
    uint32_t* wfl = smem + 4224;       // 64*132

    uint32_t* hs_priv = hs_w + (size_t)b * 32 * 1024;   // this block's FC rows

    // ---------------- prologue: weights -> registers (fp32 -> f16) ----------------
    const int unit = 8 * b + 2 * wv + p;          // this lane's hidden unit
    const int r    = g * 2048 + unit;             // this lane's gate-row
    f16x2 wh[128];                                // W_hh[r, 256c .. 256c+256)
    {
        const float4* ptr = (const float4*)(whh + (size_t)r * 2048 + 256 * c);
#pragma unroll
        for (int q = 0; q < 64; ++q) {
            float4 v = ptr[q];
            wh[2*q+0] = pk(v.x, v.y);
            wh[2*q+1] = pk(v.z, v.w);
        }
    }
    f16x2 wx[16];                                 // W_ih[r, 32c .. 32c+32)
    {
        const float4* ptr = (const float4*)(wih + (size_t)r * 256 + 32 * c);
#pragma unroll
        for (int q = 0; q < 8; ++q) {
            float4 v = ptr[q];
            wx[2*q+0] = pk(v.x, v.y);
            wx[2*q+1] = pk(v.z, v.w);
        }
    }
    // h version 0 (hprev) -> slot 0 ; x row 0 -> ldsX0 ; x row 1 -> regs
#pragma unroll
    for (int k = 0; k < 4; ++k) {
        int j = tid + 256 * k;
        ldsH0[skH(j)] = h2u(pk2(hprev2[j]));
    }
    if (tid < 128) ldsX0[skX(tid)] = h2u(pk2(x2[tid]));
    float2 xw = {0.f, 0.f};                       // x pipeline depth-2: holds row t+1 at top of iter t
    if (tid < 128) xw = x2[128 + tid];

    float cloc = cprev[unit];
    float hloc = 0.f;
    const float bsum = bih[r] + bhh[r];             // per-lane gate bias
    u32x4 prev_pays = {0, 0, 0, 0};                 // deferred hs row (swept last iter)
    int  prev_row = 0;
    bool prev_own = false;
    const ull deadline = __builtin_amdgcn_s_memrealtime() + 60000000ull; // watchdog: bail, no hang
    __syncthreads();

    // ---------------- sequential scan: ONE barrier per step ----------------
    for (int t = 0; t < SEQ; ++t) {
        uint32_t* ldsH  = (t & 1) ? ldsH1 : ldsH0;
        uint32_t* ldsXc = (t & 1) ? ldsX1 : ldsX0;   // row t (consumed now)
        uint32_t* ldsXn = (t & 1) ? ldsX0 : ldsX1;   // row t+1 (staged from regs)

        // x-projection (off critical path), 8-way ILP accumulators
        float accs[8];
#pragma unroll
        for (int q = 0; q < 8; ++q) accs[q] = 0.f;
        {
            const f16x8* xp = (const f16x8*)(ldsXc + 20 * c);
#pragma unroll
            for (int q = 0; q < 4; ++q) {
                f16x8 xv = xp[q];
#pragma unroll
                for (int d = 0; d < 4; ++d) {
                    f16x2 hv = {xv[2*d], xv[2*d+1]};
                    int idx = 4 * q + d;
                    accs[idx & 7] = __builtin_amdgcn_fdot2(wx[idx], hv, accs[idx & 7], false);
                }
            }
        }
        // stage row t+1 into the other ldsX buffer from REGISTERS (no vmem near
        // any blocking wait; barrier-ordered for next iteration's readers)
        if (tid < 128 && t + 1 < SEQ) ldsXn[skX(tid)] = h2u(pk2(xw));

        // ---- exchange: FUSED probe (gate + data in one RTT), gated fallback ----
        if (t > 0) {
            const int par = t & 1;
            const uint32_t target = (uint32_t)((t + (t & 1)) >> 1) * 8u;
            const uint32_t* cbase = ctr + (size_t)par * 8 * 128;
            const ull* mb = htag + (size_t)par * 1024 + 4 * tid;

            // one round trip: counter line (l&7) + this thread's 32B data quad
            u32x4 cv, qa, qb;
            probe_sc1(cbase + (size_t)(l & 7) * 128, mb, cv, qa, qb);
            bool valid = (qa[1] == (uint32_t)t && qa[3] == (uint32_t)t &&
                          qb[1] == (uint32_t)t && qb[3] == (uint32_t)t);
            if (!__all(valid)) {
                // gate status came free with the probe
                bool gok = (cv[0] >= target) && (cv[1] >= target) &&
                           (cv[2] >= target) && (cv[3] >= target);
                if (!__all(gok)) {
                    // proven round-5 gate loop (8 lanes x 8 lines)
                    int spins = 0;
                    for (;;) {
                        bool ok = true;
                        if (l < 8) {
                            u32x4 v = ld_ctr4(cbase + (size_t)l * 128);
                            ok = (v[0] >= target) && (v[1] >= target) &&
                                 (v[2] >= target) && (v[3] >= target);
                        }
                        if (__all(ok)) break;
                        if (spins++ > 0) {
                            if (__builtin_amdgcn_s_memrealtime() > deadline) break;
                            __builtin_amdgcn_s_sleep(1);
                        }
                    }
                }
                // re-read ONLY stale quads (gate passed -> fresh)
                while (!valid) {
                    ld32_sc1(mb, qa, qb);
                    valid = (qa[1] == (uint32_t)t && qa[3] == (uint32_t)t &&
                             qb[1] == (uint32_t)t && qb[3] == (uint32_t)t);
                    if (__builtin_amdgcn_s_memrealtime() > deadline) break;
                }
            }
            u32x4 pays = {qa[0], qa[2], qb[0], qb[2]};
            *(u32x4*)(ldsH + skH(4 * tid)) = pays;          // contiguous quad -> ds_write_b128
            // DEFERRED hs store: last iteration's swept row; ack drains under compute
            if (prev_own)
                *(u32x4*)(hs_priv + (size_t)(prev_row & 31) * 1024 + 4 * tid) = prev_pays;
            prev_pays = pays;
            prev_row  = t - 1;
            prev_own  = ((t - 1) >> 5) == b;
        }
        // prefetch x row t+2 into regs (issued AFTER the probe's vmcnt(0), so
        // it is never outstanding at any blocking wait; consumed next iter)
        if (tid < 128 && t + 2 < SEQ) xw = x2[(size_t)(t + 2) * 128 + tid];

        __syncthreads();

        // recurrent matvec from register weights, h via LDS broadcast (8-way ILP)
        {
            const f16x8* hp = (const f16x8*)(ldsH + 132 * c);
#pragma unroll
            for (int q = 0; q < 32; ++q) {
                f16x8 hv8 = hp[q];
#pragma unroll
                for (int d = 0; d < 4; ++d) {
                    f16x2 hh = {hv8[2*d], hv8[2*d+1]};
                    int idx = 4 * q + d;
                    accs[idx & 7] = __builtin_amdgcn_fdot2(wh[idx], hh, accs[idx & 7], false);
                }
            }
        }
        float acc = ((accs[0] + accs[1]) + (accs[2] + accs[3]))
                  + ((accs[4] + accs[5]) + (accs[6] + accs[7]));
        // reduce over the 8 k-chunk lanes (c = bits 0..2 of lane)
        acc += __shfl_xor(acc, 1);
        acc += __shfl_xor(acc, 2);
        acc += __shfl_xor(acc, 4);

        // one v_exp for all four gates (lane-specialized), then intra-wave gather
        float z = acc + bsum;
        const bool isg = (g == 2);
        float s  = sigf(isg ? 2.0f * z : z);
        float val = isg ? (2.0f * s - 1.0f) : s;
        const int p8 = l & 8;
        float iv = __shfl(val, p8 + 0);
        float fv = __shfl(val, p8 + 16);
        float gv = __shfl(val, p8 + 32);
        float ov = __shfl(val, p8 + 48);
        cloc = fv * cloc + iv * gv;
        hloc = ov * tanh_fast(cloc);

        // publish: tagged word per wave, then one sub-counter bump per block
        float h0 = __shfl(hloc, 0);
        float h1 = __shfl(hloc, 8);
        uint32_t pay = h2u(pk(h0, h1));
        if (l == 0) {
            ull tv = ((ull)(uint32_t)(t + 1) << 32) | (ull)pay;
            __hip_atomic_store(htag + (size_t)((t + 1) & 1) * 1024 + 4 * b + wv,
                               tv, __ATOMIC_RELAXED, __HIP_MEMORY_SCOPE_AGENT);
            if (wv == 0)
                atomicAdd(ctr + ((size_t)((t + 1) & 1) * 8 + (b & 7)) * 128 + ((b >> 3) & 3), 1u);
        }
    }

    // epilogue: flush the final deferred row (t=8191 sweep -> row 8190, block 255)
    if (prev_own)
        *(u32x4*)(hs_priv + (size_t)(prev_row & 31) * 1024 + 4 * tid) = prev_pays;

    // hT / cT outputs (fp32): lanes 0 (p=0) and 8 (p=1) of each wave hold their unit
    if (l == 0 || l == 8) {
        out[(size_t)SEQ * DOUT + unit]        = hloc;
        out[(size_t)SEQ * DOUT + HDIM + unit] = cloc;
    }

    // only block 255 needs h(8191) (= hs row 8191) -> poll tag 8192 (slot 0) on the mailbox
    if (b == 255) {
        uint32_t pay[4] = {0, 0, 0, 0};
        unsigned got = 0;
        while (got != 0xFu) {
#pragma unroll
            for (int k = 0; k < 4; ++k) {
                if (!(got & (1u << k))) {
                    ull v = __hip_atomic_load(htag + (tid + 256 * k),
                                              __ATOMIC_RELAXED, __HIP_MEMORY_SCOPE_AGENT);
                    if ((uint32_t)(v >> 32) == 8192u) {
                        pay[k] = (uint32_t)v;
                        got |= (1u << k);
                    }
                }
            }
            if (got != 0xFu) {
                if (__builtin_amdgcn_s_memrealtime() > deadline) got = 0xFu;
                __builtin_amdgcn_s_sleep(1);
            }
        }
#pragma unroll
        for (int k = 0; k < 4; ++k)
            hs_priv[(size_t)31 * 1024 + tid + 256 * k] = pay[k];
    }
    __syncthreads();

    // ---------------- output FC: rows [32b, 32b+32), 64 cols, from PRIVATE hs ----------------
    const int cc = tid & 63;
    const int rg = tid >> 6;
    const float bo = bfc[cc];
    float fca[8];
#pragma unroll
    for (int q = 0; q < 8; ++q) fca[q] = 0.f;

    for (int ch = 0; ch < 8; ++ch) {   // 8 chunks of 256 k (128 pair-words)
#pragma unroll
        for (int i = 0; i < 16; ++i) { // hs tile: [32 rows][128 words]
            int idx = tid + 256 * i;
            int rr = idx >> 7, kp = idx & 127;
            hsl[rr * 132 + kp] = hs_priv[(size_t)rr * 1024 + ch * 128 + kp]; // own writes
        }
#pragma unroll
        for (int i = 0; i < 32; ++i) { // W_fc tile: [64 cols][128 pair-words]
            int idx = tid + 256 * i;
            int c2 = idx >> 7, kp = idx & 127;
            wfl[c2 * 132 + kp] = h2u(pk2(wfc2[(size_t)c2 * 1024 + ch * 128 + kp]));
        }
        __syncthreads();
#pragma unroll 4
        for (int k4 = 0; k4 < 32; ++k4) {
            f16x8 wvv = *(const f16x8*)(wfl + cc * 132 + 4 * k4);
#pragma unroll
            for (int q = 0; q < 8; ++q) {
                f16x8 hv = *(const f16x8*)(hsl + (rg * 8 + q) * 132 + 4 * k4);
#pragma unroll
                for (int d = 0; d < 4; ++d) {
                    f16x2 a  = {hv[2*d], hv[2*d+1]};
                    f16x2 bb = {wvv[2*d], wvv[2*d+1]};
                    fca[q] = __builtin_amdgcn_fdot2(a, bb, fca[q], false);
                }
            }
        }
        __syncthreads();
    }
#pragma unroll
    for (int q = 0; q < 8; ++q) {
        size_t row = (size_t)32 * b + rg * 8 + q;
        out[row * DOUT + cc] = sigf(fca[q] + bo);
    }
}

extern "C" void kernel_launch(void* const* d_in, const int* in_sizes, int n_in,
                              void* d_out, int out_size, void* d_ws, size_t ws_size,
                              hipStream_t stream) {
    const float2* x2     = (const float2*)d_in[0];
    const float2* hprev2 = (const float2*)d_in[1];
    const float*  cprev  = (const float*)d_in[2];
    const float*  wih    = (const float*)d_in[3];
    const float*  whh    = (const float*)d_in[4];
    const float*  bih    = (const float*)d_in[5];
    const float*  bhh    = (const float*)d_in[6];
    const float2* wfc2   = (const float2*)d_in[7];
    const float*  bfc    = (const float*)d_in[8];
    float*        out    = (float*)d_out;

    char* ws = (char*)d_ws;
    uint32_t* hs_w = (uint32_t*)ws;                      // 33,554,432 B private hs slices
    ull*      htag = (ull*)(ws + 33554432);              // 16 KB (0xAA != any tag)
    uint32_t* ctr  = (uint32_t*)(ws + 33554432 + 16384); // 16 lines x 512B = 8 KB, zeroed

    hipMemsetAsync(ctr, 0, 8192, stream);   // graph-capturable
    lstm_persist<<<dim3(256), dim3(256), 0, stream>>>(
        x2, hprev2, cprev, wih, whh, bih, bhh, wfc2, bfc,
        out, hs_w, htag, ctr);
}

// Round 8
// 21976.222 us; speedup vs baseline: 2.2320x; 1.6134x over previous
//
#include <hip/hip_runtime.h>
#include <stdint.h>

typedef __fp16 f16x2 __attribute__((ext_vector_type(2)));
typedef __fp16 f16x8 __attribute__((ext_vector_type(8)));
typedef uint32_t u32x4 __attribute__((ext_vector_type(4)));
typedef unsigned long long ull;

#define SEQ  8192
#define HDIM 2048
#define DIN  256
#define DOUT 64

__device__ __forceinline__ f16x2 pk(float lo, float hi) {
    return __builtin_amdgcn_cvt_pkrtz(lo, hi);   // fp32 pair -> packed f16
}
__device__ __forceinline__ f16x2 pk2(float2 v) { return pk(v.x, v.y); }
__device__ __forceinline__ uint32_t h2u(f16x2 h) { return __builtin_bit_cast(uint32_t, h); }
__device__ __forceinline__ float sigf(float x) { return 1.0f / (1.0f + __expf(-x)); }
__device__ __forceinline__ float tanh_fast(float x) { return 2.0f * sigf(2.0f * x) - 1.0f; }

// LDS skews: chunk c's words land contiguously; chunks hit disjoint bank groups.
__device__ __forceinline__ int skH(int j) { return j + 4 * (j >> 7); }  // max 1051
__device__ __forceinline__ int skX(int j) { return j + 4 * (j >> 4); }  // max 155

// 32B load, MALL-coherent (sc1), single RTT; early-clobber so dest never aliases addr.
__device__ __forceinline__ void ld32_sc1(const ull* p, u32x4& a, u32x4& b) {
    asm volatile("global_load_dwordx4 %0, %2, off sc1\n\t"
                 "global_load_dwordx4 %1, %2, off offset:16 sc1\n\t"
                 "s_waitcnt vmcnt(0)"
                 : "=&v"(a), "=&v"(b) : "v"(p) : "memory");
}
// async 16B counter-line load: ISSUE ONLY, no wait (pipelined polling)
__device__ __forceinline__ void ld_ctr4_issue(const uint32_t* p, u32x4& v) {
    asm volatile("global_load_dwordx4 %0, %1, off sc1"
                 : "=&v"(v) : "v"(p) : "memory");
}
// wait until at most N vmem ops outstanding; ties the waited value so the
// compiler cannot hoist uses above the wait (rule: asm waitcnt + reg-only use)
__device__ __forceinline__ void wait_vm0(u32x4& v) {
    asm volatile("s_waitcnt vmcnt(0)" : "+v"(v) :: "memory");
    __builtin_amdgcn_sched_barrier(0);
}
__device__ __forceinline__ void wait_vm1(u32x4& v) {
    asm volatile("s_waitcnt vmcnt(1)" : "+v"(v) :: "memory");
    __builtin_amdgcn_sched_barrier(0);
}

__global__ void __launch_bounds__(256, 1)
lstm_persist(const float2* __restrict__ x2,       // [8192*128] fp32 pairs
             const float2* __restrict__ hprev2,   // [1024]
             const float*  __restrict__ cprev,    // [2048]
             const float*  __restrict__ wih,      // [8192*256]
             const float*  __restrict__ whh,      // [8192*2048]
             const float*  __restrict__ bih,      // [8192]
             const float*  __restrict__ bhh,      // [8192]
             const float2* __restrict__ wfc2,     // [64*1024]
             const float*  __restrict__ bfc,      // [64]
             float* __restrict__ out,             // 528384 fp32
             uint32_t* __restrict__ hs_w,         // [256 blocks][32 rows][1024 words] PRIVATE
             ull* __restrict__ htag,              // [2][1024] tagged-word mailbox
             uint32_t* __restrict__ ctr)          // [2 parity][8 lines x 4 subctrs], 512B stride, zeroed
{
    const int tid = threadIdx.x;
    const int b   = blockIdx.x;
    const int wv  = tid >> 6;        // wave id 0..3 -> units 2wv, 2wv+1
    const int l   = tid & 63;        // lane
    const int g   = l >> 4;          // gate 0..3 (i,f,g,o)
    const int p   = (l >> 3) & 1;    // unit parity
    const int c   = l & 7;           // k-chunk 0..7

    __shared__ __align__(16) uint32_t smem[12672];
    uint32_t* ldsH0 = smem;            // 1056 words
    uint32_t* ldsH1 = smem + 1056;     // 1056
    uint32_t* ldsX0 = smem + 2112;     // 160 (x row t,   t even)
    uint32_t* ldsX1 = smem + 2272;     // 160 (x row t,   t odd)
    // FC-phase reuse:
    uint32_t* hsl = smem;              // 32*132
    uint32_t* wfl = smem + 4224;       // 64*132

    uint32_t* hs_priv = hs_w + (size_t)b * 32 * 1024;   // this block's FC rows

    // ---------------- prologue: weights -> registers (fp32 -> f16) ----------------
    const int unit = 8 * b + 2 * wv + p;          // this lane's hidden unit
    const int r    = g * 2048 + unit;             // this lane's gate-row
    f16x2 wh[128];                                // W_hh[r, 256c .. 256c+256)
    {
        const float4* ptr = (const float4*)(whh + (size_t)r * 2048 + 256 * c);
#pragma unroll
        for (int q = 0; q < 64; ++q) {
            float4 v = ptr[q];
            wh[2*q+0] = pk(v.x, v.y);
            wh[2*q+1] = pk(v.z, v.w);
        }
    }
    f16x2 wx[16];                                 // W_ih[r, 32c .. 32c+32)
    {
        const float4* ptr = (const float4*)(wih + (size_t)r * 256 + 32 * c);
#pragma unroll
        for (int q = 0; q < 8; ++q) {
            float4 v = ptr[q];
            wx[2*q+0] = pk(v.x, v.y);
            wx[2*q+1] = pk(v.z, v.w);
        }
    }
    // h version 0 (hprev) -> slot 0 ; x row 0 -> ldsX0 ; x row 1 -> regs
#pragma unroll
    for (int k = 0; k < 4; ++k) {
        int j = tid + 256 * k;
        ldsH0[skH(j)] = h2u(pk2(hprev2[j]));
    }
    if (tid < 128) ldsX0[skX(tid)] = h2u(pk2(x2[tid]));
    float2 xw = {0.f, 0.f};                       // x pipeline depth-2: holds row t+1 at top of iter t
    if (tid < 128) xw = x2[128 + tid];

    float cloc = cprev[unit];
    float hloc = 0.f;
    const float bsum = bih[r] + bhh[r];             // per-lane gate bias
    u32x4 prev_pays = {0, 0, 0, 0};                 // deferred hs row (swept last iter)
    int  prev_row = 0;
    bool prev_own = false;
    const ull deadline = __builtin_amdgcn_s_memrealtime() + 60000000ull; // watchdog: bail, no hang
    __syncthreads();

    // ---------------- sequential scan: ONE barrier per step ----------------
    for (int t = 0; t < SEQ; ++t) {
        uint32_t* ldsH  = (t & 1) ? ldsH1 : ldsH0;
        uint32_t* ldsXc = (t & 1) ? ldsX1 : ldsX0;   // row t (consumed now)
        uint32_t* ldsXn = (t & 1) ? ldsX0 : ldsX1;   // row t+1 (staged from regs)

        // stage row t+1 FIRST: its use of xw makes the compiler drain all of
        // last iteration's vmem (xw prefetch + deferred store ack) HERE, so the
        // poll issued next has a clean vmcnt window.
        if (tid < 128 && t + 1 < SEQ) ldsXn[skX(tid)] = h2u(pk2(xw));

        const int par = t & 1;
        const uint32_t target = (uint32_t)((t + (t & 1)) >> 1) * 8u;
        const uint32_t* cbase = ctr + (size_t)par * 8 * 128;

        // EARLY poll issue: overlaps x-projection below (one RTT hidden).
        u32x4 pv;
        if (t > 0 && l < 8) ld_ctr4_issue(cbase + (size_t)l * 128, pv);

        // x-projection (pure LDS/VALU -> runs under the poll), 8-way ILP
        float accs[8];
#pragma unroll
        for (int q = 0; q < 8; ++q) accs[q] = 0.f;
        {
            const f16x8* xp = (const f16x8*)(ldsXc + 20 * c);
#pragma unroll
            for (int q = 0; q < 4; ++q) {
                f16x8 xv = xp[q];
#pragma unroll
                for (int d = 0; d < 4; ++d) {
                    f16x2 hv = {xv[2*d], xv[2*d+1]};
                    int idx = 4 * q + d;
                    accs[idx & 7] = __builtin_amdgcn_fdot2(wx[idx], hv, accs[idx & 7], false);
                }
            }
        }

        // ---- exchange ----
        if (t > 0) {
            // collect the early poll
            wait_vm0(pv);
            bool ok = (l >= 8) || ((pv[0] >= target) && (pv[1] >= target) &&
                                   (pv[2] >= target) && (pv[3] >= target));
            if (!__all(ok)) {
                // pipelined gate loop: 2 polls in flight, in-order retirement
                // (vmcnt counts retire in issue order) -> sampling period ~RTT/2
                u32x4 pa, pb;
                if (l < 8) { ld_ctr4_issue(cbase + (size_t)l * 128, pa);
                             ld_ctr4_issue(cbase + (size_t)l * 128, pb); }
                int phase = 0;
                for (;;) {
                    bool ok2 = true;
                    if (phase == 0) {
                        wait_vm1(pa);
                        if (l < 8) ok2 = (pa[0] >= target) && (pa[1] >= target) &&
                                         (pa[2] >= target) && (pa[3] >= target);
                    } else {
                        wait_vm0(pb);
                        if (l < 8) ok2 = (pb[0] >= target) && (pb[1] >= target) &&
                                         (pb[2] >= target) && (pb[3] >= target);
                    }
                    if (__all(ok2)) break;
                    if (__builtin_amdgcn_s_memrealtime() > deadline) break;
                    if (l < 8) {
                        if (phase == 0) ld_ctr4_issue(cbase + (size_t)l * 128, pa);
                        else            ld_ctr4_issue(cbase + (size_t)l * 128, pb);
                    }
                    phase ^= 1;
                }
                // drain any poll still in flight before the one-shot sweep
                asm volatile("s_waitcnt vmcnt(0)" ::: "memory");
            }
            // one-shot data read (32B quad = producer block tid's 4 words), tag-validated
            const ull* mb = htag + (size_t)par * 1024 + 4 * tid;
            u32x4 qa, qb;
            for (;;) {
                ld32_sc1(mb, qa, qb);
                if (qa[1] == (uint32_t)t && qa[3] == (uint32_t)t &&
                    qb[1] == (uint32_t)t && qb[3] == (uint32_t)t) break;
                if (__builtin_amdgcn_s_memrealtime() > deadline) break;
                __builtin_amdgcn_s_sleep(1);
            }
            u32x4 pays = {qa[0], qa[2], qb[0], qb[2]};
            *(u32x4*)(ldsH + skH(4 * tid)) = pays;          // contiguous quad -> ds_write_b128
            // DEFERRED hs store: last iteration's swept row; ack drains under compute
            if (prev_own)
                *(u32x4*)(hs_priv + (size_t)(prev_row & 31) * 1024 + 4 * tid) = prev_pays;
            prev_pays = pays;
            prev_row  = t - 1;
            prev_own  = ((t - 1) >> 5) == b;
        }
        // prefetch x row t+2 into regs (issued AFTER the sweep's vmcnt(0), so
        // it is never outstanding at any blocking wait; consumed next iter)
        if (tid < 128 && t + 2 < SEQ) xw = x2[(size_t)(t + 2) * 128 + tid];

        __syncthreads();

        // recurrent matvec from register weights, h via LDS broadcast (8-way ILP)
        {
            const f16x8* hp = (const f16x8*)(ldsH + 132 * c);
#pragma unroll
            for (int q = 0; q < 32; ++q) {
                f16x8 hv8 = hp[q];
#pragma unroll
                for (int d = 0; d < 4; ++d) {
                    f16x2 hh = {hv8[2*d], hv8[2*d+1]};
                    int idx = 4 * q + d;
                    accs[idx & 7] = __builtin_amdgcn_fdot2(wh[idx], hh, accs[idx & 7], false);
                }
            }
        }
        float acc = ((accs[0] + accs[1]) + (accs[2] + accs[3]))
                  + ((accs[4] + accs[5]) + (accs[6] + accs[7]));
        // reduce over the 8 k-chunk lanes (c = bits 0..2 of lane)
        acc += __shfl_xor(acc, 1);
        acc += __shfl_xor(acc, 2);
        acc += __shfl_xor(acc, 4);

        // one v_exp for all four gates (lane-specialized), then intra-wave gather
        float z = acc + bsum;
        const bool isg = (g == 2);
        float s  = sigf(isg ? 2.0f * z : z);
        float val = isg ? (2.0f * s - 1.0f) : s;
        const int p8 = l & 8;
        float iv = __shfl(val, p8 + 0);
        float fv = __shfl(val, p8 + 16);
        float gv = __shfl(val, p8 + 32);
        float ov = __shfl(val, p8 + 48);
        cloc = fv * cloc + iv * gv;
        hloc = ov * tanh_fast(cloc);

        // publish: tagged word per wave, then one sub-counter bump per block
        float h0 = __shfl(hloc, 0);
        float h1 = __shfl(hloc, 8);
        uint32_t pay = h2u(pk(h0, h1));
        if (l == 0) {
            ull tv = ((ull)(uint32_t)(t + 1) << 32) | (ull)pay;
            __hip_atomic_store(htag + (size_t)((t + 1) & 1) * 1024 + 4 * b + wv,
                               tv, __ATOMIC_RELAXED, __HIP_MEMORY_SCOPE_AGENT);
            if (wv == 0)
                atomicAdd(ctr + ((size_t)((t + 1) & 1) * 8 + (b & 7)) * 128 + ((b >> 3) & 3), 1u);
        }
    }

    // epilogue: flush the final deferred row (t=8191 sweep -> row 8190, block 255)
    if (prev_own)
        *(u32x4*)(hs_priv + (size_t)(prev_row & 31) * 1024 + 4 * tid) = prev_pays;

    // hT / cT outputs (fp32): lanes 0 (p=0) and 8 (p=1) of each wave hold their unit
    if (l == 0 || l == 8) {
        out[(size_t)SEQ * DOUT + unit]        = hloc;
        out[(size_t)SEQ * DOUT + HDIM + unit] = cloc;
    }

    // only block 255 needs h(8191) (= hs row 8191) -> poll tag 8192 (slot 0) on the mailbox
    if (b == 255) {
        uint32_t pay[4] = {0, 0, 0, 0};
        unsigned got = 0;
        while (got != 0xFu) {
#pragma unroll
            for (int k = 0; k < 4; ++k) {
                if (!(got & (1u << k))) {
                    ull v = __hip_atomic_load(htag + (tid + 256 * k),
                                              __ATOMIC_RELAXED, __HIP_MEMORY_SCOPE_AGENT);
                    if ((uint32_t)(v >> 32) == 8192u) {
                        pay[k] = (uint32_t)v;
                        got |= (1u << k);
                    }
                }
            }
            if (got != 0xFu) {
                if (__builtin_amdgcn_s_memrealtime() > deadline) got = 0xFu;
                __builtin_amdgcn_s_sleep(1);
            }
        }
#pragma unroll
        for (int k = 0; k < 4; ++k)
            hs_priv[(size_t)31 * 1024 + tid + 256 * k] = pay[k];
    }
    __syncthreads();

    // ---------------- output FC: rows [32b, 32b+32), 64 cols, from PRIVATE hs ----------------
    const int cc = tid & 63;
    const int rg = tid >> 6;
    const float bo = bfc[cc];
    float fca[8];
#pragma unroll
    for (int q = 0; q < 8; ++q) fca[q] = 0.f;

    for (int ch = 0; ch < 8; ++ch) {   // 8 chunks of 256 k (128 pair-words)
#pragma unroll
        for (int i = 0; i < 16; ++i) { // hs tile: [32 rows][128 words]
            int idx = tid + 256 * i;
            int rr = idx >> 7, kp = idx & 127;
            hsl[rr * 132 + kp] = hs_priv[(size_t)rr * 1024 + ch * 128 + kp]; // own writes
        }
#pragma unroll
        for (int i = 0; i < 32; ++i) { // W_fc tile: [64 cols][128 pair-words]
            int idx = tid + 256 * i;
            int c2 = idx >> 7, kp = idx & 127;
            wfl[c2 * 132 + kp] = h2u(pk2(wfc2[(size_t)c2 * 1024 + ch * 128 + kp]));
        }
        __syncthreads();
#pragma unroll 4
        for (int k4 = 0; k4 < 32; ++k4) {
            f16x8 wvv = *(const f16x8*)(wfl + cc * 132 + 4 * k4);
#pragma unroll
            for (int q = 0; q < 8; ++q) {
                f16x8 hv = *(const f16x8*)(hsl + (rg * 8 + q) * 132 + 4 * k4);
#pragma unroll
                for (int d = 0; d < 4; ++d) {
                    f16x2 a  = {hv[2*d], hv[2*d+1]};
                    f16x2 bb = {wvv[2*d], wvv[2*d+1]};
                    fca[q] = __builtin_amdgcn_fdot2(a, bb, fca[q], false);
                }
            }
        }
        __syncthreads();
    }
#pragma unroll
    for (int q = 0; q < 8; ++q) {
        size_t row = (size_t)32 * b + rg * 8 + q;
        out[row * DOUT + cc] = sigf(fca[q] + bo);
    }
}

extern "C" void kernel_launch(void* const* d_in, const int* in_sizes, int n_in,
                              void* d_out, int out_size, void* d_ws, size_t ws_size,
                              hipStream_t stream) {
    const float2* x2     = (const float2*)d_in[0];
    const float2* hprev2 = (const float2*)d_in[1];
    const float*  cprev  = (const float*)d_in[2];
    const float*  wih    = (const float*)d_in[3];
    const float*  whh    = (const float*)d_in[4];
    const float*  bih    = (const float*)d_in[5];
    const float*  bhh    = (const float*)d_in[6];
    const float2* wfc2   = (const float2*)d_in[7];
    const float*  bfc    = (const float*)d_in[8];
    float*        out    = (float*)d_out;

    char* ws = (char*)d_ws;
    uint32_t* hs_w = (uint32_t*)ws;                      // 33,554,432 B private hs slices
    ull*      htag = (ull*)(ws + 33554432);              // 16 KB (0xAA != any tag)
    uint32_t* ctr  = (uint32_t*)(ws + 33554432 + 16384); // 16 lines x 512B = 8 KB, zeroed

    hipMemsetAsync(ctr, 0, 8192, stream);   // graph-capturable
    lstm_persist<<<dim3(256), dim3(256), 0, stream>>>(
        x2, hprev2, cprev, wih, whh, bih, bhh, wfc2, bfc,
        out, hs_w, htag, ctr);
}